// Round 13
// baseline (541.385 us; speedup 1.0000x reference)
//
#include <hip/hip_runtime.h>
#include <stdint.h>

#define NN 8000            // nodes
#define UU 64              // units
#define EE 64000           // edges per support
#define BB 32              // batch
#define NB 256000          // NN*BB rows of the logical GEMM
#define HXS 512000         // NN*UU (per-batch stride in hx)

typedef __attribute__((ext_vector_type(8))) __bf16 bf16x8;
typedef __attribute__((ext_vector_type(4))) float f32x4;
typedef __attribute__((ext_vector_type(4))) unsigned int u32x4;
typedef __attribute__((ext_vector_type(2))) unsigned int u32x2;

__device__ __forceinline__ unsigned short f2bf(float f){
  unsigned int u = __builtin_bit_cast(unsigned int, f);
  u += 0x7fffu + ((u >> 16) & 1u);
  return (unsigned short)(u >> 16);
}
__device__ __forceinline__ unsigned int pack2(float a, float b){
  return (unsigned int)f2bf(a) | ((unsigned int)f2bf(b) << 16);
}
__device__ __forceinline__ float bflo(unsigned int w){ return __builtin_bit_cast(float, w << 16); }
__device__ __forceinline__ float bfhi(unsigned int w){ return __builtin_bit_cast(float, w & 0xffff0000u); }
__device__ __forceinline__ float bfu(unsigned short v){ return __builtin_bit_cast(float, (unsigned int)v << 16); }

__device__ __forceinline__ void acc8(float* a, float v, uint4 q){
  a[0]+=v*bflo(q.x); a[1]+=v*bfhi(q.x); a[2]+=v*bflo(q.y); a[3]+=v*bfhi(q.y);
  a[4]+=v*bflo(q.z); a[5]+=v*bfhi(q.z); a[6]+=v*bflo(q.w); a[7]+=v*bfhi(q.w);
}

// async global->LDS, 16B per lane; LDS dest = wave-uniform base + lane*16 (linear).
__device__ __forceinline__ void stage16(const unsigned short* g, unsigned short* ldsbase){
  __builtin_amdgcn_global_load_lds((const __attribute__((address_space(1))) void*)g,
                                   (__attribute__((address_space(3))) void*)ldsbase, 16, 0, 0);
}

__device__ __forceinline__ void ntstore16(uint4 v, uint4* p){
  u32x4 ov = {v.x, v.y, v.z, v.w};
  __builtin_nontemporal_store(ov, (u32x4*)p);
}
__device__ __forceinline__ void ntstore8(uint2 v, uint2* p){
  u32x2 ov = {v.x, v.y};
  __builtin_nontemporal_store(ov, (u32x2*)p);
}

// ---------------- CSR build ----------------
__global__ void k_hist(const int* __restrict__ r0, const int* __restrict__ r1, int* __restrict__ cnt){
  int i = blockIdx.x * 256 + threadIdx.x;
  if (i < 2*EE){
    int s = (i >= EE);
    int r = s ? r1[i - EE] : r0[i];
    atomicAdd(&cnt[s*NN + r], 1);
  }
}

__global__ __launch_bounds__(1024) void k_scan(const int* __restrict__ cnt, int* __restrict__ row_ptr, int* __restrict__ rp_work){
  int sup = blockIdx.x;
  const int* c = cnt + sup*NN;
  __shared__ int part[1024];
  int t = threadIdx.x;
  int loc[8]; int s = 0;
  #pragma unroll
  for (int j=0;j<8;j++){ int idx=t*8+j; int v = (idx<NN)? c[idx]:0; loc[j]=s; s+=v; }
  part[t]=s; __syncthreads();
  for (int o=1;o<1024;o<<=1){
    int v = (t>=o)? part[t-o]:0;
    __syncthreads();
    part[t]+=v;
    __syncthreads();
  }
  int pre = (t>0)? part[t-1]:0;
  #pragma unroll
  for (int j=0;j<8;j++){ int idx=t*8+j; if(idx<NN){ int e=pre+loc[j]; row_ptr[sup*(NN+1)+idx]=e; rp_work[sup*NN+idx]=e; } }
  if (t==1023) row_ptr[sup*(NN+1)+NN] = part[1023];
}

__global__ void k_scatter(const int* __restrict__ r0, const int* __restrict__ c0, const float* __restrict__ v0,
                          const int* __restrict__ r1, const int* __restrict__ c1, const float* __restrict__ v1,
                          int* __restrict__ rp_work, uint2* __restrict__ edge_s){
  int i = blockIdx.x * 256 + threadIdx.x;
  if (i < 2*EE){
    int s = (i >= EE);
    int e = s ? i - EE : i;
    int r  = s ? r1[e] : r0[e];
    int cc = s ? c1[e] : c0[e];
    float vv = s ? v1[e] : v0[e];
    int pos = atomicAdd(&rp_work[s*NN + r], 1);
    uint2 ev; ev.x = (unsigned int)cc; ev.y = __builtin_bit_cast(unsigned int, vv);
    edge_s[s*EE + pos] = ev;
  }
}

// ---------------- weight repack (Chebyshev absorbed, column-permuted) ----------------
__global__ void k_wpack(const float* __restrict__ W_ru, const float* __restrict__ W_c,
                        unsigned short* __restrict__ Wru_t, unsigned short* __restrict__ Wc_t){
  int i = blockIdx.x * 256 + threadIdx.x;   // 352*192 total
  int k = i / 192; int oo = i % 192;
  const float* W; int ld, NC; unsigned short* dst; int c;
  if (oo < 128){ W = W_ru; ld = 128; NC = 128; dst = Wru_t; c = oo; }
  else         { W = W_c;  ld = 64;  NC = 64;  dst = Wc_t;  c = oo - 128; }
  int o = 4*(c & 15) + ((c >> 4) & 3);
  int wcol = (c >= 64) ? 64 + o : o;
  float v = 0.f;
  if (k < 330){
    int m, fb;
    if (k < 320){ m = k >> 6; fb = (2 + (k & 63)) * 5; }
    else        { int j = k - 320; m = j >> 1; fb = (j & 1) * 5; }
    if      (m==0) v = W[(fb+0)*ld+wcol] - W[(fb+2)*ld+wcol] - W[(fb+4)*ld+wcol];
    else if (m==1) v = W[(fb+1)*ld+wcol];
    else if (m==2) v = 2.f*W[(fb+2)*ld+wcol];
    else if (m==3) v = W[(fb+3)*ld+wcol];
    else           v = 2.f*W[(fb+4)*ld+wcol];
  }
  int dstoff;
  if (k < 320) dstoff = (k>>6)*NC*64 + c*64 + (k&63);
  else         dstoff = 320*NC + c*32 + (k-320);
  dst[dstoff] = f2bf(v);
}

// ---------------- build x0 ----------------
// state slab per m: row-major [n*32+b][64u] bf16 (4KB per node)
// xi slab per m: [8 s][NN] uint4 (4 bins of dword)
__global__ void k_x0(const float* __restrict__ inputs, const float* __restrict__ hx,
                     uint4* __restrict__ xs0q, unsigned int* __restrict__ xi0){
  int n = blockIdx.x, t = threadIdx.x;
  int b = t >> 3, ug = t & 7;
  const float4 h0 = *(const float4*)(hx + (size_t)b*HXS + n*64 + ug*8);
  const float4 h1 = *(const float4*)(hx + (size_t)b*HXS + n*64 + ug*8 + 4);
  uint4 o;
  o.x = pack2(h0.x, h0.y); o.y = pack2(h0.z, h0.w);
  o.z = pack2(h1.x, h1.y); o.w = pack2(h1.z, h1.w);
  xs0q[((size_t)n*32 + b)*8 + ug] = o;
  if (t < 32){
    int bb = t;
    const float2 g = *(const float2*)(inputs + (size_t)bb*(NN*2) + n*2);
    xi0[(((size_t)(bb>>2)*NN) + n)*4 + (bb&3)] = pack2(g.x, g.y);
  }
}

// ---------------- SpMM: persistent XCD-pinned blocks ----------------
// 2048 blocks, all co-resident (8 blocks/CU). slice = blockIdx&7 == XCD under
// round-robin dispatch. Each slice's 1024 waves grid-stride its 16000 (node,sup)
// tasks (sup0 first, then sup1) + folded input-feature tasks. Per-XCD working
// set = one 4.096MB source-slab slice, pinned in its L2 for the whole dispatch.
template<bool WITH_IN>
__global__ __launch_bounds__(256) void k_spmm(const int* __restrict__ row_ptr, const uint2* __restrict__ edge_s,
                                              unsigned short* xsS, uint4* xi4,
                                              int supE0, int msrc0, int mdst0,
                                              int supE1, int msrc1, int mdst1){
  const int slice = blockIdx.x & 7;
  const int wslot = (blockIdx.x >> 3)*4 + (threadIdx.x >> 6);   // 0..1023 within slice
  const int lane = threadIdx.x & 63;
  const int off = slice*256 + lane*4;            // shorts: slice 512B + lane 8B
  const int NTASK = WITH_IN ? 18000 : 16000;

  for (int task = wslot; task < NTASK; task += 1024){
    if (task < 16000){
      int si = (task >= 8000) ? 1 : 0;
      int n = task - si*8000;
      int supE = si ? supE1 : supE0;
      int msrc = si ? msrc1 : msrc0;
      int mdst = si ? mdst1 : mdst0;
      const unsigned short* srcS = xsS + (size_t)msrc*(NN*2048);
      unsigned short* dstS = xsS + (size_t)mdst*(NN*2048);
      int beg = __builtin_amdgcn_readfirstlane(row_ptr[supE*(NN+1)+n]);
      int end = __builtin_amdgcn_readfirstlane(row_ptr[supE*(NN+1)+n+1]);
      const uint2* es = edge_s + supE*EE;
      float a0=0.f, a1=0.f, a2=0.f, a3=0.f;
      int e = beg;
      for (; e + 2 <= end; e += 2){
        uint2 ev0 = es[e], ev1 = es[e+1];
        int c0 = __builtin_amdgcn_readfirstlane((int)ev0.x);
        int c1 = __builtin_amdgcn_readfirstlane((int)ev1.x);
        float v0 = __builtin_bit_cast(float, __builtin_amdgcn_readfirstlane(ev0.y));
        float v1 = __builtin_bit_cast(float, __builtin_amdgcn_readfirstlane(ev1.y));
        uint2 q0 = *(const uint2*)(srcS + (size_t)c0*2048 + off);
        uint2 q1 = *(const uint2*)(srcS + (size_t)c1*2048 + off);
        a0 += v0*bflo(q0.x); a1 += v0*bfhi(q0.x); a2 += v0*bflo(q0.y); a3 += v0*bfhi(q0.y);
        a0 += v1*bflo(q1.x); a1 += v1*bfhi(q1.x); a2 += v1*bflo(q1.y); a3 += v1*bfhi(q1.y);
      }
      if (e < end){
        uint2 ev = es[e];
        int c = __builtin_amdgcn_readfirstlane((int)ev.x);
        float v = __builtin_bit_cast(float, __builtin_amdgcn_readfirstlane(ev.y));
        uint2 q = *(const uint2*)(srcS + (size_t)c*2048 + off);
        a0 += v*bflo(q.x); a1 += v*bfhi(q.x); a2 += v*bflo(q.y); a3 += v*bfhi(q.y);
      }
      uint2 o; o.x = pack2(a0, a1); o.y = pack2(a2, a3);
      ntstore8(o, (uint2*)(dstS + (size_t)n*2048 + off));
    } else if (WITH_IN){
      // input-feature diffusion: task encodes (s, si, 64-node block); per-lane node
      int it = task - 16000;                 // 0..1999
      int s = it & 7;
      int rest = it >> 3;                    // 0..249
      int si = rest & 1;
      int n = (rest >> 1)*64 + lane;         // (rest>>1) in 0..124 -> n < 8000
      int supE = si ? supE1 : supE0;
      int msrc = si ? msrc1 : msrc0;
      int mdst = si ? mdst1 : mdst0;
      size_t sb = (size_t)(msrc*8 + s)*NN, db = (size_t)(mdst*8 + s)*NN;
      int beg = row_ptr[supE*(NN+1)+n], end = row_ptr[supE*(NN+1)+n+1];
      const uint2* es = edge_s + supE*EE;
      float ai[8] = {0.f,0.f,0.f,0.f,0.f,0.f,0.f,0.f};
      for (int e = beg; e < end; ++e){
        uint2 ev = es[e];
        float v = __builtin_bit_cast(float, ev.y);
        uint4 qi = xi4[sb + ev.x];
        acc8(ai, v, qi);
      }
      uint4 oi;
      oi.x = pack2(ai[0],ai[1]); oi.y = pack2(ai[2],ai[3]); oi.z = pack2(ai[4],ai[5]); oi.w = pack2(ai[6],ai[7]);
      ntstore16(oi, &xi4[db + n]);
    }
  }
}

// ---------------- GEMM (R7/R11 structure): A global->reg dbuf, B small LDS dbuf, 3 blocks/CU ----------------
template<int NCOL, bool IS_RU>
__global__ __launch_bounds__(256, 3) void k_gemm(unsigned short* xsS,                   // state slabs (slab0 = hx-bf16 / r*hx target)
                                                 const unsigned int* __restrict__ xsI,  // input dwords (8-slice layout)
                                                 const unsigned short* __restrict__ Wp, // packed [m][NCOL][64] + tail [NCOL][32]
                                                 const float* __restrict__ bias,
                                                 const float* __restrict__ hx,
                                                 float* cout,
                                                 unsigned short* ubuf){
  constexpr int CF = NCOL / 16;
  __shared__ unsigned short Bl[2][NCOL*64];
  __shared__ unsigned short Bt[NCOL*32];
  const int t = threadIdx.x;
  const int wv = t >> 6;
  const int l = t & 63;
  const int lr = l & 15;
  const int lg = l >> 4;
  const int R0 = blockIdx.x * 128;

  auto stageB = [&](int m, int buf){
    #pragma unroll
    for (int i=0;i<NCOL*8/256;i++){
      int g = t + i*256;
      int rr = g >> 3, c = g & 7;
      const unsigned short* gp = Wp + (size_t)(m*NCOL + rr)*64 + ((c ^ (rr&7)) << 3);
      stage16(gp, &Bl[buf][(size_t)(i*256 + wv*64)*8]);
    }
  };

  // per-wave A row bases (shorts; layout row-major [gemm_row][64])
  size_t abase[2];
  #pragma unroll
  for (int rf=0; rf<2; rf++)
    abase[rf] = (size_t)(R0 + wv*32 + rf*16 + lr)*64;
  auto loadA = [&](int m, uint4* dst){
    #pragma unroll
    for (int ks=0; ks<2; ks++)
      #pragma unroll
      for (int rf=0; rf<2; rf++)
        dst[ks*2+rf] = *(const uint4*)(xsS + (size_t)m*(NN*2048) + abase[rf] + ks*32 + lg*8);
  };

  // ---- prologue: A(m=0), tail frags, B0 + Btail ----
  uint4 aC[4], aN[4];
  loadA(0, aC);
  uint4 aT[2];
  #pragma unroll
  for (int rf=0; rf<2; rf++){
    int row = R0 + wv*32 + rf*16 + lr;
    int n = row >> 5, b = row & 31;
    size_t ib = (((size_t)(b>>2))*NN + n)*4 + (b&3);
    unsigned int q0=0u,q1=0u,q2=0u,q3=0u;
    if (lg == 0){
      q0 = xsI[ib];
      q1 = xsI[(size_t)8*NN*4 + ib];
      q2 = xsI[(size_t)16*NN*4 + ib];
      q3 = xsI[(size_t)24*NN*4 + ib];
    } else if (lg == 1){
      q0 = xsI[(size_t)32*NN*4 + ib];
    }
    uint4 qq; qq.x=q0; qq.y=q1; qq.z=q2; qq.w=q3;
    aT[rf] = qq;
  }
  stageB(0, 0);
  {
    #pragma unroll
    for (int i=0;i<NCOL*4/256;i++){
      int g = t + i*256;
      int rr = g >> 2, c = g & 3;
      const unsigned short* gp = Wp + (size_t)320*NCOL + rr*32 + ((c ^ (rr&3)) << 3);
      stage16(gp, &Bt[(size_t)(i*256 + wv*64)*8]);
    }
  }
  __syncthreads();

  f32x4 acc[2][CF];
  const f32x4 zero = {0.f,0.f,0.f,0.f};
  #pragma unroll
  for (int rf=0; rf<2; rf++)
    #pragma unroll
    for (int cf=0; cf<CF; cf++) acc[rf][cf] = zero;

  #pragma unroll
  for (int m=0; m<5; m++){
    int cur = m & 1;
    if (m < 4){
      stageB(m+1, cur^1);
      loadA(m+1, aN);
    }
    #pragma unroll
    for (int ks=0; ks<2; ks++){
      #pragma unroll
      for (int cf=0; cf<CF; cf++){
        int col = cf*16 + lr;
        int chunk = (ks*4 + lg) ^ (col & 7);
        bf16x8 bv = __builtin_bit_cast(bf16x8, *(const uint4*)(&Bl[cur][col*64 + chunk*8]));
        acc[0][cf] = __builtin_amdgcn_mfma_f32_16x16x32_bf16(__builtin_bit_cast(bf16x8, aC[ks*2+0]), bv, acc[0][cf], 0, 0, 0);
        acc[1][cf] = __builtin_amdgcn_mfma_f32_16x16x32_bf16(__builtin_bit_cast(bf16x8, aC[ks*2+1]), bv, acc[1][cf], 0, 0, 0);
      }
    }
    __syncthreads();
    #pragma unroll
    for (int i=0;i<4;i++) aC[i] = aN[i];
  }

  // ---- tail K-step (input features) ----
  #pragma unroll
  for (int cf=0; cf<CF; cf++){
    int col = cf*16 + lr;
    int chunk = lg ^ (col & 3);
    bf16x8 bv = __builtin_bit_cast(bf16x8, *(const uint4*)(&Bt[col*32 + chunk*8]));
    acc[0][cf] = __builtin_amdgcn_mfma_f32_16x16x32_bf16(__builtin_bit_cast(bf16x8, aT[0]), bv, acc[0][cf], 0, 0, 0);
    acc[1][cf] = __builtin_amdgcn_mfma_f32_16x16x32_bf16(__builtin_bit_cast(bf16x8, aT[1]), bv, acc[1][cf], 0, 0, 0);
  }

  // ---- epilogue (col c -> unit 4*lr+cf; vectorized stores) ----
  #pragma unroll
  for (int rf=0; rf<2; rf++){
    #pragma unroll
    for (int reg=0; reg<4; reg++){
      int row = R0 + wv*32 + rf*16 + (lg << 2) + reg;
      int n = row >> 5, b = row & 31;
      size_t rowoff = (size_t)b*HXS + (size_t)n*UU;
      size_t slot0 = (size_t)row*64;
      int o0 = lr << 2;
      if constexpr (IS_RU){
        uint2 hv = *(const uint2*)(xsS + slot0 + o0);   // hx bf16 (slab0, pre-overwrite)
        unsigned short rr4[4], uu4[4];
        #pragma unroll
        for (int cf=0; cf<4; cf++){
          int o = o0 + cf;
          float vr = acc[rf][cf][reg]   + bias[o];
          float vu = acc[rf][cf+4][reg] + bias[64+o];
          float sgr = 1.f/(1.f + __expf(-vr));
          float sgu = 1.f/(1.f + __expf(-vu));
          float h = bfu(((const unsigned short*)&hv)[cf]);
          rr4[cf] = f2bf(sgr * h);
          uu4[cf] = f2bf(sgu);
        }
        *(uint2*)(xsS + slot0 + o0) = *(uint2*)rr4;
        *(uint2*)(ubuf + rowoff + o0) = *(uint2*)uu4;
      } else {
        float4 hv = *(const float4*)(hx + rowoff + o0);
        uint2 uv = *(const uint2*)(ubuf + rowoff + o0);
        float4 ov;
        #pragma unroll
        for (int cf=0; cf<4; cf++){
          float cc = tanhf(acc[rf][cf][reg] + bias[o0+cf]);
          float uu = bfu(((const unsigned short*)&uv)[cf]);
          float h  = ((const float*)&hv)[cf];
          ((float*)&ov)[cf] = uu*h + (1.f - uu)*cc;
        }
        *(float4*)(cout + rowoff + o0) = ov;
      }
    }
  }
}

// ---------------- launcher ----------------
extern "C" void kernel_launch(void* const* d_in, const int* in_sizes, int n_in,
                              void* d_out, int out_size, void* d_ws, size_t ws_size,
                              hipStream_t stream){
  const float* inputs = (const float*)d_in[0];
  const float* hx     = (const float*)d_in[1];
  const int*   row0   = (const int*)d_in[2];
  const int*   col0   = (const int*)d_in[3];
  const float* val0   = (const float*)d_in[4];
  const int*   row1   = (const int*)d_in[5];
  const int*   col1   = (const int*)d_in[6];
  const float* val1   = (const float*)d_in[7];
  const float* W_ru   = (const float*)d_in[8];
  const float* b_ru   = (const float*)d_in[9];
  const float* W_c    = (const float*)d_in[10];
  const float* b_c    = (const float*)d_in[11];
  float* out = (float*)d_out;

  char* ws = (char*)d_ws;
  size_t off = 0;
  auto alloc = [&](size_t bytes) -> void* {
    void* p = ws + off;
    off += (bytes + 255) & ~(size_t)255;
    return p;
  };
  unsigned short* xsS   = (unsigned short*)alloc((size_t)5*NN*2048*2);  // 163.84 MB
  unsigned int*   xsI   = (unsigned int*)  alloc((size_t)5*8*NN*16);    //   5.12 MB
  unsigned short* u_buf = (unsigned short*)alloc((size_t)NB*64*2);      //  32.77 MB
  unsigned short* Wru_t = (unsigned short*)alloc((size_t)128*352*2);
  unsigned short* Wc_t  = (unsigned short*)alloc((size_t)64*352*2);
  int*   row_ptr = (int*)  alloc(2*(NN+1)*4);
  uint2* edge_s  = (uint2*)alloc((size_t)2*EE*8);
  int*   cnt     = (int*)  alloc(2*NN*4);
  int*   rp_work = (int*)  alloc(2*NN*4);
  (void)ws_size; (void)in_sizes; (void)n_in; (void)out_size;

  hipMemsetAsync(cnt, 0, 2*NN*4, stream);
  k_hist<<<(2*EE + 255)/256, 256, 0, stream>>>(row0, row1, cnt);
  k_scan<<<2, 1024, 0, stream>>>(cnt, row_ptr, rp_work);
  k_scatter<<<(2*EE + 255)/256, 256, 0, stream>>>(row0, col0, val0, row1, col1, val1, rp_work, edge_s);
  k_wpack<<<(352*192)/256, 256, 0, stream>>>(W_ru, W_c, Wru_t, Wc_t);
  k_x0<<<NN, 256, 0, stream>>>(inputs, hx, (uint4*)xsS, (unsigned int*)xsI);

  uint4* xi4 = (uint4*)xsI;

  // gconv 1: hop1 (m0 -> m1, m3), hop2 (m1 -> m2 ; m3 -> m4); persistent XCD-pinned
  k_spmm<true ><<<2048, 256, 0, stream>>>(row_ptr, edge_s, xsS, xi4, 0, 0, 1, 1, 0, 3);
  k_spmm<true ><<<2048, 256, 0, stream>>>(row_ptr, edge_s, xsS, xi4, 0, 1, 2, 1, 3, 4);
  k_gemm<128, true><<<2000, 256, 0, stream>>>(xsS, xsI, Wru_t, b_ru, hx, nullptr, u_buf);

  // gconv 2: state part = r*hx (slab 0); input diffusion reused from gconv1
  k_spmm<false><<<2048, 256, 0, stream>>>(row_ptr, edge_s, xsS, xi4, 0, 0, 1, 1, 0, 3);
  k_spmm<false><<<2048, 256, 0, stream>>>(row_ptr, edge_s, xsS, xi4, 0, 1, 2, 1, 3, 4);
  k_gemm<64, false><<<2000, 256, 0, stream>>>(xsS, xsI, Wc_t, b_c, hx, out, u_buf);
}

// Round 14
// 396.267 us; speedup vs baseline: 1.3662x; 1.3662x over previous
//
#include <hip/hip_runtime.h>
#include <stdint.h>

#define NN 8000            // nodes
#define UU 64              // units
#define EE 64000           // edges per support
#define BB 32              // batch
#define NB 256000          // NN*BB rows of the logical GEMM
#define HXS 512000         // NN*UU (per-batch stride in hx)

typedef __attribute__((ext_vector_type(8))) __bf16 bf16x8;
typedef __attribute__((ext_vector_type(4))) float f32x4;
typedef __attribute__((ext_vector_type(4))) unsigned int u32x4;

__device__ __forceinline__ unsigned short f2bf(float f){
  unsigned int u = __builtin_bit_cast(unsigned int, f);
  u += 0x7fffu + ((u >> 16) & 1u);
  return (unsigned short)(u >> 16);
}
__device__ __forceinline__ unsigned int pack2(float a, float b){
  return (unsigned int)f2bf(a) | ((unsigned int)f2bf(b) << 16);
}
__device__ __forceinline__ float bflo(unsigned int w){ return __builtin_bit_cast(float, w << 16); }
__device__ __forceinline__ float bfhi(unsigned int w){ return __builtin_bit_cast(float, w & 0xffff0000u); }
__device__ __forceinline__ float bfu(unsigned short v){ return __builtin_bit_cast(float, (unsigned int)v << 16); }

__device__ __forceinline__ void acc8(float* a, float v, uint4 q){
  a[0]+=v*bflo(q.x); a[1]+=v*bfhi(q.x); a[2]+=v*bflo(q.y); a[3]+=v*bfhi(q.y);
  a[4]+=v*bflo(q.z); a[5]+=v*bfhi(q.z); a[6]+=v*bflo(q.w); a[7]+=v*bfhi(q.w);
}

// async global->LDS, 16B per lane; LDS dest = wave-uniform base + lane*16 (linear).
__device__ __forceinline__ void stage16(const unsigned short* g, unsigned short* ldsbase){
  __builtin_amdgcn_global_load_lds((const __attribute__((address_space(1))) void*)g,
                                   (__attribute__((address_space(3))) void*)ldsbase, 16, 0, 0);
}

__device__ __forceinline__ void ntstore16(uint4 v, uint4* p){
  u32x4 ov = {v.x, v.y, v.z, v.w};
  __builtin_nontemporal_store(ov, (u32x4*)p);
}

// ---------------- CSR build ----------------
__global__ void k_hist(const int* __restrict__ r0, const int* __restrict__ r1, int* __restrict__ cnt){
  int i = blockIdx.x * 256 + threadIdx.x;
  if (i < 2*EE){
    int s = (i >= EE);
    int r = s ? r1[i - EE] : r0[i];
    atomicAdd(&cnt[s*NN + r], 1);
  }
}

__global__ __launch_bounds__(1024) void k_scan(const int* __restrict__ cnt, int* __restrict__ row_ptr, int* __restrict__ rp_work){
  int sup = blockIdx.x;
  const int* c = cnt + sup*NN;
  __shared__ int part[1024];
  int t = threadIdx.x;
  int loc[8]; int s = 0;
  #pragma unroll
  for (int j=0;j<8;j++){ int idx=t*8+j; int v = (idx<NN)? c[idx]:0; loc[j]=s; s+=v; }
  part[t]=s; __syncthreads();
  for (int o=1;o<1024;o<<=1){
    int v = (t>=o)? part[t-o]:0;
    __syncthreads();
    part[t]+=v;
    __syncthreads();
  }
  int pre = (t>0)? part[t-1]:0;
  #pragma unroll
  for (int j=0;j<8;j++){ int idx=t*8+j; if(idx<NN){ int e=pre+loc[j]; row_ptr[sup*(NN+1)+idx]=e; rp_work[sup*NN+idx]=e; } }
  if (t==1023) row_ptr[sup*(NN+1)+NN] = part[1023];
}

__global__ void k_scatter(const int* __restrict__ r0, const int* __restrict__ c0, const float* __restrict__ v0,
                          const int* __restrict__ r1, const int* __restrict__ c1, const float* __restrict__ v1,
                          int* __restrict__ rp_work, uint2* __restrict__ edge_s){
  int i = blockIdx.x * 256 + threadIdx.x;
  if (i < 2*EE){
    int s = (i >= EE);
    int e = s ? i - EE : i;
    int r  = s ? r1[e] : r0[e];
    int cc = s ? c1[e] : c0[e];
    float vv = s ? v1[e] : v0[e];
    int pos = atomicAdd(&rp_work[s*NN + r], 1);
    uint2 ev; ev.x = (unsigned int)cc; ev.y = __builtin_bit_cast(unsigned int, vv);
    edge_s[s*EE + pos] = ev;
  }
}

// ---------------- weight repack (Chebyshev absorbed, column-permuted) ----------------
// GEMM col c -> output unit o = 4*(c&15) + ((c>>4)&3); r/u block kept by c<64.
// Wp layout: m 0..4: [m][NCOL][64k] ; tail at 320*NCOL: [NCOL][32k]
__global__ void k_wpack(const float* __restrict__ W_ru, const float* __restrict__ W_c,
                        unsigned short* __restrict__ Wru_t, unsigned short* __restrict__ Wc_t){
  int i = blockIdx.x * 256 + threadIdx.x;   // 352*192 total
  int k = i / 192; int oo = i % 192;
  const float* W; int ld, NC; unsigned short* dst; int c;
  if (oo < 128){ W = W_ru; ld = 128; NC = 128; dst = Wru_t; c = oo; }
  else         { W = W_c;  ld = 64;  NC = 64;  dst = Wc_t;  c = oo - 128; }
  int o = 4*(c & 15) + ((c >> 4) & 3);
  int wcol = (c >= 64) ? 64 + o : o;
  float v = 0.f;
  if (k < 330){
    int m, fb;
    if (k < 320){ m = k >> 6; fb = (2 + (k & 63)) * 5; }
    else        { int j = k - 320; m = j >> 1; fb = (j & 1) * 5; }
    if      (m==0) v = W[(fb+0)*ld+wcol] - W[(fb+2)*ld+wcol] - W[(fb+4)*ld+wcol];
    else if (m==1) v = W[(fb+1)*ld+wcol];
    else if (m==2) v = 2.f*W[(fb+2)*ld+wcol];
    else if (m==3) v = W[(fb+3)*ld+wcol];
    else           v = 2.f*W[(fb+4)*ld+wcol];
  }
  int dstoff;
  if (k < 320) dstoff = (k>>6)*NC*64 + c*64 + (k&63);
  else         dstoff = 320*NC + c*32 + (k-320);
  dst[dstoff] = f2bf(v);
}

// ---------------- build x0 ----------------
// state slab per m: [16 slice][NN][2 bin][64 u] bf16 (slice = b>>1, bin = b&1)
// xi slab per m: [8 s][NN] uint4 (4 bins of dword)
__global__ void k_x0(const float* __restrict__ inputs, const float* __restrict__ hx,
                     uint4* __restrict__ xs0q, unsigned int* __restrict__ xi0){
  int n = blockIdx.x, t = threadIdx.x;
  int b = t >> 3, ug = t & 7;
  const float4 h0 = *(const float4*)(hx + (size_t)b*HXS + n*64 + ug*8);
  const float4 h1 = *(const float4*)(hx + (size_t)b*HXS + n*64 + ug*8 + 4);
  uint4 o;
  o.x = pack2(h0.x, h0.y); o.y = pack2(h0.z, h0.w);
  o.z = pack2(h1.x, h1.y); o.w = pack2(h1.z, h1.w);
  xs0q[(size_t)(b>>1)*(NN*16) + (size_t)n*16 + (b&1)*8 + ug] = o;
  if (t < 32){
    int bb = t;
    const float2 g = *(const float2*)(inputs + (size_t)bb*(NN*2) + n*2);
    xi0[(((size_t)(bb>>2)*NN) + n)*4 + (bb&3)] = pack2(g.x, g.y);
  }
}

// ---------------- SpMM (16-sliced, XCD-sequenced; optional nt dst; uint2 edge meta) ----------------
// state: 16000 blocks = 8 xcd x (2 sup x [500 grp slice=xcd | 500 grp slice=xcd+8])
// block = 16 subgroups x 16 lanes; subgroup owns one node row-slice (256B).
template<bool WITH_IN, bool NTDST>
__global__ void k_spmm(const int* __restrict__ row_ptr, const uint2* __restrict__ edge_s,
                       uint4* xs4, uint4* xi4,
                       int srcA, int dstA, int srcB, int dstB){
  int bid = blockIdx.x;
  if (WITH_IN && bid >= 16000){
    int b2 = bid - 16000;
    int s = b2 & 7, supi = (b2 >> 3) & 1, chunk = b2 >> 4;
    int n = chunk*256 + threadIdx.x;
    if (n >= NN) return;
    int msrc = supi ? srcB : srcA, mdst = supi ? dstB : dstA;
    size_t sb = (size_t)(msrc*8 + s)*NN, db = (size_t)(mdst*8 + s)*NN;
    int beg = row_ptr[supi*(NN+1)+n], end = row_ptr[supi*(NN+1)+n+1];
    const uint2* es = edge_s + supi*EE;
    float ai[8] = {0.f,0.f,0.f,0.f,0.f,0.f,0.f,0.f};
    for (int e = beg; e < end; ++e){
      uint2 ev = es[e];
      float v = __builtin_bit_cast(float, ev.y);
      uint4 qi = xi4[sb + ev.x];
      acc8(ai, v, qi);
    }
    uint4 oi;
    oi.x = pack2(ai[0],ai[1]); oi.y = pack2(ai[2],ai[3]); oi.z = pack2(ai[4],ai[5]); oi.w = pack2(ai[6],ai[7]);
    if (NTDST) ntstore16(oi, &xi4[db + n]); else xi4[db + n] = oi;
    return;
  }
  int xcd = bid & 7;
  int seq = bid >> 3;
  int supi = (seq >= 1000) ? 1 : 0;
  int seq2 = seq - supi*1000;
  int slice = (seq2 < 500) ? xcd : (xcd + 8);
  int group = (seq2 < 500) ? seq2 : (seq2 - 500);
  int sub = threadIdx.x >> 4, lane = threadIdx.x & 15;
  int n = group*16 + sub;
  int msrc = supi ? srcB : srcA, mdst = supi ? dstB : dstA;
  size_t sS = (size_t)msrc*(NN*256) + (size_t)slice*(NN*16);
  size_t dS = (size_t)mdst*(NN*256) + (size_t)slice*(NN*16);
  int beg = row_ptr[supi*(NN+1)+n], end = row_ptr[supi*(NN+1)+n+1];
  const uint2* es = edge_s + supi*EE;

  float a[8] = {0.f,0.f,0.f,0.f,0.f,0.f,0.f,0.f};
  int e = beg;
  for (; e + 4 <= end; e += 4){
    uint2 e0 = es[e], e1 = es[e+1], e2 = es[e+2], e3 = es[e+3];
    uint4 q0 = xs4[sS + (size_t)e0.x*16 + lane];
    uint4 q1 = xs4[sS + (size_t)e1.x*16 + lane];
    uint4 q2 = xs4[sS + (size_t)e2.x*16 + lane];
    uint4 q3 = xs4[sS + (size_t)e3.x*16 + lane];
    acc8(a, __builtin_bit_cast(float, e0.y), q0);
    acc8(a, __builtin_bit_cast(float, e1.y), q1);
    acc8(a, __builtin_bit_cast(float, e2.y), q2);
    acc8(a, __builtin_bit_cast(float, e3.y), q3);
  }
  for (; e < end; ++e){
    uint2 ev = es[e];
    uint4 q = xs4[sS + (size_t)ev.x*16 + lane];
    acc8(a, __builtin_bit_cast(float, ev.y), q);
  }
  uint4 o;
  o.x = pack2(a[0],a[1]); o.y = pack2(a[2],a[3]); o.z = pack2(a[4],a[5]); o.w = pack2(a[6],a[7]);
  if (NTDST) ntstore16(o, &xs4[dS + (size_t)n*16 + lane]);
  else       xs4[dS + (size_t)n*16 + lane] = o;
}

// ---------------- GEMM: 4 independent 32-row waves, A global->reg dbuf, B via small LDS dbuf ----------------
template<int NCOL, bool IS_RU>
__global__ __launch_bounds__(256, 3) void k_gemm(unsigned short* xsS,                   // state slabs (slab0 = hx-bf16 / r*hx target)
                                                 const unsigned int* __restrict__ xsI,  // input dwords (8-slice layout)
                                                 const unsigned short* __restrict__ Wp, // packed [m][NCOL][64] + tail [NCOL][32]
                                                 const float* __restrict__ bias,
                                                 const float* __restrict__ hx,
                                                 float* cout,
                                                 unsigned short* ubuf){
  constexpr int CF = NCOL / 16;
  __shared__ unsigned short Bl[2][NCOL*64];
  __shared__ unsigned short Bt[NCOL*32];
  const int t = threadIdx.x;
  const int wv = t >> 6;
  const int l = t & 63;
  const int lr = l & 15;
  const int lg = l >> 4;
  const int R0 = blockIdx.x * 128;

  auto stageB = [&](int m, int buf){
    #pragma unroll
    for (int i=0;i<NCOL*8/256;i++){
      int g = t + i*256;
      int rr = g >> 3, c = g & 7;
      const unsigned short* gp = Wp + (size_t)(m*NCOL + rr)*64 + ((c ^ (rr&7)) << 3);
      stage16(gp, &Bl[buf][(size_t)(i*256 + wv*64)*8]);
    }
  };

  // per-wave A row bases (shorts)
  size_t abase[2];
  #pragma unroll
  for (int rf=0; rf<2; rf++){
    int row = R0 + wv*32 + rf*16 + lr;
    int n = row >> 5, b = row & 31;
    abase[rf] = (size_t)(b>>1)*(NN*128) + (size_t)n*128 + (b&1)*64;
  }
  auto loadA = [&](int m, uint4* dst){
    #pragma unroll
    for (int ks=0; ks<2; ks++)
      #pragma unroll
      for (int rf=0; rf<2; rf++)
        dst[ks*2+rf] = *(const uint4*)(xsS + (size_t)m*(NN*2048) + abase[rf] + ks*32 + lg*8);
  };

  // ---- prologue: A(m=0), tail frags, B0 + Btail ----
  uint4 aC[4], aN[4];
  loadA(0, aC);
  uint4 aT[2];
  #pragma unroll
  for (int rf=0; rf<2; rf++){
    int row = R0 + wv*32 + rf*16 + lr;
    int n = row >> 5, b = row & 31;
    size_t ib = (((size_t)(b>>2))*NN + n)*4 + (b&3);
    unsigned int q0=0u,q1=0u,q2=0u,q3=0u;
    if (lg == 0){
      q0 = xsI[ib];
      q1 = xsI[(size_t)8*NN*4 + ib];
      q2 = xsI[(size_t)16*NN*4 + ib];
      q3 = xsI[(size_t)24*NN*4 + ib];
    } else if (lg == 1){
      q0 = xsI[(size_t)32*NN*4 + ib];
    }
    uint4 qq; qq.x=q0; qq.y=q1; qq.z=q2; qq.w=q3;
    aT[rf] = qq;
  }
  stageB(0, 0);
  {
    #pragma unroll
    for (int i=0;i<NCOL*4/256;i++){
      int g = t + i*256;
      int rr = g >> 2, c = g & 3;
      const unsigned short* gp = Wp + (size_t)320*NCOL + rr*32 + ((c ^ (rr&3)) << 3);
      stage16(gp, &Bt[(size_t)(i*256 + wv*64)*8]);
    }
  }
  __syncthreads();

  f32x4 acc[2][CF];
  const f32x4 zero = {0.f,0.f,0.f,0.f};
  #pragma unroll
  for (int rf=0; rf<2; rf++)
    #pragma unroll
    for (int cf=0; cf<CF; cf++) acc[rf][cf] = zero;

  #pragma unroll
  for (int m=0; m<5; m++){
    int cur = m & 1;
    if (m < 4){
      stageB(m+1, cur^1);
      loadA(m+1, aN);
    }
    #pragma unroll
    for (int ks=0; ks<2; ks++){
      #pragma unroll
      for (int cf=0; cf<CF; cf++){
        int col = cf*16 + lr;
        int chunk = (ks*4 + lg) ^ (col & 7);
        bf16x8 bv = __builtin_bit_cast(bf16x8, *(const uint4*)(&Bl[cur][col*64 + chunk*8]));
        acc[0][cf] = __builtin_amdgcn_mfma_f32_16x16x32_bf16(__builtin_bit_cast(bf16x8, aC[ks*2+0]), bv, acc[0][cf], 0, 0, 0);
        acc[1][cf] = __builtin_amdgcn_mfma_f32_16x16x32_bf16(__builtin_bit_cast(bf16x8, aC[ks*2+1]), bv, acc[1][cf], 0, 0, 0);
      }
    }
    __syncthreads();
    #pragma unroll
    for (int i=0;i<4;i++) aC[i] = aN[i];
  }

  // ---- tail K-step (input features) ----
  #pragma unroll
  for (int cf=0; cf<CF; cf++){
    int col = cf*16 + lr;
    int chunk = lg ^ (col & 3);
    bf16x8 bv = __builtin_bit_cast(bf16x8, *(const uint4*)(&Bt[col*32 + chunk*8]));
    acc[0][cf] = __builtin_amdgcn_mfma_f32_16x16x32_bf16(__builtin_bit_cast(bf16x8, aT[0]), bv, acc[0][cf], 0, 0, 0);
    acc[1][cf] = __builtin_amdgcn_mfma_f32_16x16x32_bf16(__builtin_bit_cast(bf16x8, aT[1]), bv, acc[1][cf], 0, 0, 0);
  }

  // ---- epilogue (col c -> unit 4*lr+cf; vectorized stores) ----
  #pragma unroll
  for (int rf=0; rf<2; rf++){
    #pragma unroll
    for (int reg=0; reg<4; reg++){
      int row = R0 + wv*32 + rf*16 + (lg << 2) + reg;
      int n = row >> 5, b = row & 31;
      size_t rowoff = (size_t)b*HXS + (size_t)n*UU;
      size_t slot0 = (size_t)(b>>1)*(NN*128) + (size_t)n*128 + (b&1)*64;
      int o0 = lr << 2;
      if constexpr (IS_RU){
        uint2 hv = *(const uint2*)(xsS + slot0 + o0);   // hx bf16 (slab0, pre-overwrite)
        unsigned short rr4[4], uu4[4];
        #pragma unroll
        for (int cf=0; cf<4; cf++){
          int o = o0 + cf;
          float vr = acc[rf][cf][reg]   + bias[o];
          float vu = acc[rf][cf+4][reg] + bias[64+o];
          float sgr = 1.f/(1.f + __expf(-vr));
          float sgu = 1.f/(1.f + __expf(-vu));
          float h = bfu(((const unsigned short*)&hv)[cf]);
          rr4[cf] = f2bf(sgr * h);
          uu4[cf] = f2bf(sgu);
        }
        *(uint2*)(xsS + slot0 + o0) = *(uint2*)rr4;
        *(uint2*)(ubuf + rowoff + o0) = *(uint2*)uu4;
      } else {
        float4 hv = *(const float4*)(hx + rowoff + o0);
        uint2 uv = *(const uint2*)(ubuf + rowoff + o0);
        float4 ov;
        #pragma unroll
        for (int cf=0; cf<4; cf++){
          float cc = tanhf(acc[rf][cf][reg] + bias[o0+cf]);
          float uu = bfu(((const unsigned short*)&uv)[cf]);
          float h  = ((const float*)&hv)[cf];
          ((float*)&ov)[cf] = uu*h + (1.f - uu)*cc;
        }
        *(float4*)(cout + rowoff + o0) = ov;
      }
    }
  }
}

// ---------------- launcher ----------------
extern "C" void kernel_launch(void* const* d_in, const int* in_sizes, int n_in,
                              void* d_out, int out_size, void* d_ws, size_t ws_size,
                              hipStream_t stream){
  const float* inputs = (const float*)d_in[0];
  const float* hx     = (const float*)d_in[1];
  const int*   row0   = (const int*)d_in[2];
  const int*   col0   = (const int*)d_in[3];
  const float* val0   = (const float*)d_in[4];
  const int*   row1   = (const int*)d_in[5];
  const int*   col1   = (const int*)d_in[6];
  const float* val1   = (const float*)d_in[7];
  const float* W_ru   = (const float*)d_in[8];
  const float* b_ru   = (const float*)d_in[9];
  const float* W_c    = (const float*)d_in[10];
  const float* b_c    = (const float*)d_in[11];
  float* out = (float*)d_out;

  char* ws = (char*)d_ws;
  size_t off = 0;
  auto alloc = [&](size_t bytes) -> void* {
    void* p = ws + off;
    off += (bytes + 255) & ~(size_t)255;
    return p;
  };
  unsigned short* xsS   = (unsigned short*)alloc((size_t)5*NN*2048*2);  // 163.84 MB
  unsigned int*   xsI   = (unsigned int*)  alloc((size_t)5*8*NN*16);    //   5.12 MB
  unsigned short* u_buf = (unsigned short*)alloc((size_t)NB*64*2);      //  32.77 MB
  unsigned short* Wru_t = (unsigned short*)alloc((size_t)128*352*2);
  unsigned short* Wc_t  = (unsigned short*)alloc((size_t)64*352*2);
  int*   row_ptr = (int*)  alloc(2*(NN+1)*4);
  uint2* edge_s  = (uint2*)alloc((size_t)2*EE*8);
  int*   cnt     = (int*)  alloc(2*NN*4);
  int*   rp_work = (int*)  alloc(2*NN*4);
  (void)ws_size; (void)in_sizes; (void)n_in; (void)out_size;

  hipMemsetAsync(cnt, 0, 2*NN*4, stream);
  k_hist<<<(2*EE + 255)/256, 256, 0, stream>>>(row0, row1, cnt);
  k_scan<<<2, 1024, 0, stream>>>(cnt, row_ptr, rp_work);
  k_scatter<<<(2*EE + 255)/256, 256, 0, stream>>>(row0, col0, val0, row1, col1, val1, rp_work, edge_s);
  k_wpack<<<(352*192)/256, 256, 0, stream>>>(W_ru, W_c, Wru_t, Wc_t);
  k_x0<<<NN, 256, 0, stream>>>(inputs, hx, (uint4*)xsS, (unsigned int*)xsI);

  uint4* xs4 = (uint4*)xsS;
  uint4* xi4 = (uint4*)xsI;

  // gconv 1: hop1 (cached dst: slabs 1,3 are hop2 gather sources), hop2 (nt dst: slabs 2,4 only streamed by GEMM)
  k_spmm<true , false><<<16512, 256, 0, stream>>>(row_ptr, edge_s, xs4, xi4, 0, 1, 0, 3);
  k_spmm<true , true ><<<16512, 256, 0, stream>>>(row_ptr, edge_s, xs4, xi4, 1, 2, 3, 4);
  k_gemm<128, true><<<2000, 256, 0, stream>>>(xsS, xsI, Wru_t, b_ru, hx, nullptr, u_buf);

  // gconv 2: state part = r*hx (slab 0); input diffusion reused from gconv1
  k_spmm<false, false><<<16000, 256, 0, stream>>>(row_ptr, edge_s, xs4, xi4, 0, 1, 0, 3);
  k_spmm<false, true ><<<16000, 256, 0, stream>>>(row_ptr, edge_s, xs4, xi4, 1, 2, 3, 4);
  k_gemm<64, false><<<2000, 256, 0, stream>>>(xsS, xsI, Wc_t, b_c, hx, out, u_buf);
}